// Round 1
// baseline (1268.025 us; speedup 1.0000x reference)
//
#include <hip/hip_runtime.h>
#include <hip/hip_bf16.h>
#include <cstddef>

// ---------------------------------------------------------------------------
// sparse_attn: transformer encoder block on levels 2 & 3, fp32 correctness-first
// ---------------------------------------------------------------------------

#define TILE 64
#define BK 16

// NCHW (N=2) -> [L=N*S, C=256] row-major
__global__ __launch_bounds__(256) void nchw_to_lc(const float* __restrict__ f,
                                                  float* __restrict__ src,
                                                  int S) {
    int idx = blockIdx.x * 256 + threadIdx.x;  // over L*256
    int l = idx >> 8, c = idx & 255;
    int n = l / S, hw = l % S;
    src[idx] = f[((size_t)(n * 256 + c)) * S + hw];
}

// [L,C] -> NCHW (N=2)
__global__ __launch_bounds__(256) void lc_to_nchw(const float* __restrict__ y,
                                                  float* __restrict__ out,
                                                  int S) {
    int idx = blockIdx.x * 256 + threadIdx.x;  // over N*C*S in out layout
    int n = idx / (256 * S);
    int rem = idx - n * 256 * S;
    int c = rem / S;
    int hw = rem - c * S;
    out[idx] = y[((size_t)(n * S + hw)) * 256 + c];
}

// C[M,N] = A[M,K] @ W[N,K]^T + bias[N]  (+ optional relu / residual)
// EPI: 0 = bias only, 1 = bias+relu, 2 = bias+residual(res[M,N])
template <int EPI>
__global__ __launch_bounds__(256) void gemm_kernel(const float* __restrict__ A,
                                                   const float* __restrict__ W,
                                                   const float* __restrict__ bias,
                                                   const float* __restrict__ res,
                                                   float* __restrict__ out,
                                                   int M, int N, int K) {
    __shared__ float As[TILE][BK + 1];
    __shared__ float Ws[TILE][BK + 1];
    int tid = threadIdx.x;
    int tx = tid & 15, ty = tid >> 4;
    int m0 = blockIdx.y * TILE, n0 = blockIdx.x * TILE;
    int lrow = tid >> 2;          // 0..63
    int lcg = (tid & 3) * 4;      // 0,4,8,12
    float acc[4][4] = {};

    for (int k0 = 0; k0 < K; k0 += BK) {
        float4 av = *(const float4*)&A[(size_t)(m0 + lrow) * K + k0 + lcg];
        As[lrow][lcg + 0] = av.x; As[lrow][lcg + 1] = av.y;
        As[lrow][lcg + 2] = av.z; As[lrow][lcg + 3] = av.w;
        float4 wv = *(const float4*)&W[(size_t)(n0 + lrow) * K + k0 + lcg];
        Ws[lrow][lcg + 0] = wv.x; Ws[lrow][lcg + 1] = wv.y;
        Ws[lrow][lcg + 2] = wv.z; Ws[lrow][lcg + 3] = wv.w;
        __syncthreads();
#pragma unroll
        for (int kk = 0; kk < BK; ++kk) {
            float a[4], b[4];
#pragma unroll
            for (int i = 0; i < 4; ++i) a[i] = As[ty * 4 + i][kk];
#pragma unroll
            for (int j = 0; j < 4; ++j) b[j] = Ws[tx * 4 + j][kk];
#pragma unroll
            for (int i = 0; i < 4; ++i)
#pragma unroll
                for (int j = 0; j < 4; ++j) acc[i][j] += a[i] * b[j];
        }
        __syncthreads();
    }

#pragma unroll
    for (int i = 0; i < 4; ++i) {
        int cm = m0 + ty * 4 + i;
#pragma unroll
        for (int j = 0; j < 4; ++j) {
            int cn = n0 + tx * 4 + j;
            float v = acc[i][j] + bias[cn];
            if (EPI == 1) v = fmaxf(v, 0.f);
            if (EPI == 2) v += res[(size_t)cm * N + cn];
            out[(size_t)cm * N + cn] = v;
        }
    }
}

// attention: one block per (query row, head). qkv layout [L, 768]:
// q at col h*32, k at 256+h*32, v at 512+h*32. Writes o[L,256].
__global__ __launch_bounds__(256) void attn_kernel(const float* __restrict__ qkv,
                                                   const float* __restrict__ u,
                                                   float* __restrict__ o,
                                                   int L, int S) {
    __shared__ float sc[2048];
    __shared__ float red[256];
    __shared__ float qs[32];
    int ql = blockIdx.x;
    int h = blockIdx.y;
    int t = threadIdx.x;
    const float scale = 0.17677669529663687f;  // 32^-0.5

    if (t < 32) qs[t] = qkv[(size_t)ql * 768 + h * 32 + t] * scale;
    __syncthreads();

    int qpos = ql % S, qfr = ql / S;
    float lmax = -1e30f;
    for (int kl = t; kl < L; kl += 256) {
        const float* kr = &qkv[(size_t)kl * 768 + 256 + h * 32];
        float dot = 0.f;
#pragma unroll
        for (int d = 0; d < 32; ++d) dot += qs[d] * kr[d];
        float m = (u[(size_t)ql * L + kl] >= 0.1f ? 1.f : 0.f)
                + ((kl % S) == qpos ? 1.f : 0.f)
                + ((kl / S) == qfr ? 1.f : 0.f);
        float s = dot + m;
        sc[kl] = s;
        lmax = fmaxf(lmax, s);
    }
    red[t] = lmax;
    __syncthreads();
    for (int s2 = 128; s2 > 0; s2 >>= 1) {
        if (t < s2) red[t] = fmaxf(red[t], red[t + s2]);
        __syncthreads();
    }
    float mx = red[0];
    __syncthreads();

    float lsum = 0.f;
    for (int kl = t; kl < L; kl += 256) {
        float e = __expf(sc[kl] - mx);
        sc[kl] = e;
        lsum += e;
    }
    red[t] = lsum;
    __syncthreads();
    for (int s2 = 128; s2 > 0; s2 >>= 1) {
        if (t < s2) red[t] += red[t + s2];
        __syncthreads();
    }
    float inv = 1.f / red[0];
    __syncthreads();

    // PV: 8 groups of 32 threads; thread owns dim d, group strides keys
    int d = t & 31, g = t >> 5;
    float acc = 0.f;
    for (int kl = g; kl < L; kl += 8)
        acc += sc[kl] * qkv[(size_t)kl * 768 + 512 + h * 32 + d];
    red[t] = acc;
    __syncthreads();
    if (t < 32) {
        float s = 0.f;
#pragma unroll
        for (int g2 = 0; g2 < 8; ++g2) s += red[g2 * 32 + t];
        o[(size_t)ql * 256 + h * 32 + t] = s * inv;
    }
}

// LayerNorm over C=256, one block per row
__global__ __launch_bounds__(256) void ln_kernel(const float* __restrict__ in,
                                                 const float* __restrict__ g,
                                                 const float* __restrict__ b,
                                                 float* __restrict__ out) {
    __shared__ float red[256];
    int row = blockIdx.x, t = threadIdx.x;
    float v = in[(size_t)row * 256 + t];
    red[t] = v;
    __syncthreads();
    for (int s = 128; s > 0; s >>= 1) {
        if (t < s) red[t] += red[t + s];
        __syncthreads();
    }
    float mean = red[0] * (1.f / 256.f);
    __syncthreads();
    float d = v - mean;
    red[t] = d * d;
    __syncthreads();
    for (int s = 128; s > 0; s >>= 1) {
        if (t < s) red[t] += red[t + s];
        __syncthreads();
    }
    float var = red[0] * (1.f / 256.f);
    out[(size_t)row * 256 + t] = d * rsqrtf(var + 1e-5f) * g[t] + b[t];
}

// ---------------------------------------------------------------------------

struct Params {
    const float *Wqkv, *bqkv, *Wo, *bo, *g1, *b1, *Wfc1, *bfc1, *Wfc2, *bfc2, *g2, *b2;
};

static void run_level(const float* f, const float* u, int S, int L,
                      float* out, float* ws, const Params& p, hipStream_t stream) {
    // workspace layout (floats), sized for L=2048
    float* src  = ws;                 // 524288
    float* qkv  = ws + 524288;        // 1572864
    float* obuf = ws + 2097152;       // 524288  (also reused for final y)
    float* t1   = ws + 2621440;       // 524288  (also reused for t2)
    float* x    = ws + 3145728;       // 524288
    float* hbuf = ws + 3670016;       // 2097152

    nchw_to_lc<<<L, 256, 0, stream>>>(f, src, S);
    gemm_kernel<0><<<dim3(768 / TILE, L / TILE), 256, 0, stream>>>(
        src, p.Wqkv, p.bqkv, nullptr, qkv, L, 768, 256);
    attn_kernel<<<dim3(L, 8), 256, 0, stream>>>(qkv, u, obuf, L, S);
    gemm_kernel<2><<<dim3(256 / TILE, L / TILE), 256, 0, stream>>>(
        obuf, p.Wo, p.bo, src, t1, L, 256, 256);
    ln_kernel<<<L, 256, 0, stream>>>(t1, p.g1, p.b1, x);
    gemm_kernel<1><<<dim3(1024 / TILE, L / TILE), 256, 0, stream>>>(
        x, p.Wfc1, p.bfc1, nullptr, hbuf, L, 1024, 256);
    gemm_kernel<2><<<dim3(256 / TILE, L / TILE), 256, 0, stream>>>(
        hbuf, p.Wfc2, p.bfc2, x, t1, L, 256, 1024);
    ln_kernel<<<L, 256, 0, stream>>>(t1, p.g2, p.b2, obuf);
    lc_to_nchw<<<L, 256, 0, stream>>>(obuf, out, S);
}

extern "C" void kernel_launch(void* const* d_in, const int* in_sizes, int n_in,
                              void* d_out, int out_size, void* d_ws, size_t ws_size,
                              hipStream_t stream) {
    const float* f0 = (const float*)d_in[0];
    const float* f1 = (const float*)d_in[1];
    const float* f2 = (const float*)d_in[2];
    const float* f3 = (const float*)d_in[3];
    const float* u2 = (const float*)d_in[4];
    const float* u3 = (const float*)d_in[5];
    Params p;
    p.Wqkv = (const float*)d_in[6];  p.bqkv = (const float*)d_in[7];
    p.Wo   = (const float*)d_in[8];  p.bo   = (const float*)d_in[9];
    p.g1   = (const float*)d_in[10]; p.b1   = (const float*)d_in[11];
    p.Wfc1 = (const float*)d_in[12]; p.bfc1 = (const float*)d_in[13];
    p.Wfc2 = (const float*)d_in[14]; p.bfc2 = (const float*)d_in[15];
    p.g2   = (const float*)d_in[16]; p.b2   = (const float*)d_in[17];

    float* out = (float*)d_out;
    float* ws = (float*)d_ws;

    // f0, f1 pass through
    hipMemcpyAsync(out, f0, (size_t)3276800 * 4, hipMemcpyDeviceToDevice, stream);
    hipMemcpyAsync(out + 3276800, f1, (size_t)819200 * 4, hipMemcpyDeviceToDevice, stream);

    // level 2: N=2, S=1024, L=2048
    run_level(f2, u2, 1024, 2048, out + 4096000, ws, p, stream);
    // level 3: N=2, S=256, L=512
    run_level(f3, u3, 256, 512, out + 4620288, ws, p, stream);
}

// Round 2
// 642.264 us; speedup vs baseline: 1.9743x; 1.9743x over previous
//
#include <hip/hip_runtime.h>
#include <hip/hip_bf16.h>
#include <cstddef>

// ---------------------------------------------------------------------------
// sparse_attn: transformer encoder block on levels 2 & 3.
// Round 2: flash-style tiled attention (was 74% of runtime, latency-bound).
// ---------------------------------------------------------------------------

#define TILE 64
#define BK 16

// NCHW (N=2) -> [L=N*S, C=256] row-major
__global__ __launch_bounds__(256) void nchw_to_lc(const float* __restrict__ f,
                                                  float* __restrict__ src,
                                                  int S) {
    int idx = blockIdx.x * 256 + threadIdx.x;  // over L*256
    int l = idx >> 8, c = idx & 255;
    int n = l / S, hw = l % S;
    src[idx] = f[((size_t)(n * 256 + c)) * S + hw];
}

// [L,C] -> NCHW (N=2)
__global__ __launch_bounds__(256) void lc_to_nchw(const float* __restrict__ y,
                                                  float* __restrict__ out,
                                                  int S) {
    int idx = blockIdx.x * 256 + threadIdx.x;  // over N*C*S in out layout
    int n = idx / (256 * S);
    int rem = idx - n * 256 * S;
    int c = rem / S;
    int hw = rem - c * S;
    out[idx] = y[((size_t)(n * S + hw)) * 256 + c];
}

// C[M,N] = A[M,K] @ W[N,K]^T + bias[N]  (+ optional relu / residual)
// EPI: 0 = bias only, 1 = bias+relu, 2 = bias+residual(res[M,N])
template <int EPI>
__global__ __launch_bounds__(256) void gemm_kernel(const float* __restrict__ A,
                                                   const float* __restrict__ W,
                                                   const float* __restrict__ bias,
                                                   const float* __restrict__ res,
                                                   float* __restrict__ out,
                                                   int M, int N, int K) {
    __shared__ float As[TILE][BK + 1];
    __shared__ float Ws[TILE][BK + 1];
    int tid = threadIdx.x;
    int tx = tid & 15, ty = tid >> 4;
    int m0 = blockIdx.y * TILE, n0 = blockIdx.x * TILE;
    int lrow = tid >> 2;          // 0..63
    int lcg = (tid & 3) * 4;      // 0,4,8,12
    float acc[4][4] = {};

    for (int k0 = 0; k0 < K; k0 += BK) {
        float4 av = *(const float4*)&A[(size_t)(m0 + lrow) * K + k0 + lcg];
        As[lrow][lcg + 0] = av.x; As[lrow][lcg + 1] = av.y;
        As[lrow][lcg + 2] = av.z; As[lrow][lcg + 3] = av.w;
        float4 wv = *(const float4*)&W[(size_t)(n0 + lrow) * K + k0 + lcg];
        Ws[lrow][lcg + 0] = wv.x; Ws[lrow][lcg + 1] = wv.y;
        Ws[lrow][lcg + 2] = wv.z; Ws[lrow][lcg + 3] = wv.w;
        __syncthreads();
#pragma unroll
        for (int kk = 0; kk < BK; ++kk) {
            float a[4], b[4];
#pragma unroll
            for (int i = 0; i < 4; ++i) a[i] = As[ty * 4 + i][kk];
#pragma unroll
            for (int j = 0; j < 4; ++j) b[j] = Ws[tx * 4 + j][kk];
#pragma unroll
            for (int i = 0; i < 4; ++i)
#pragma unroll
                for (int j = 0; j < 4; ++j) acc[i][j] += a[i] * b[j];
        }
        __syncthreads();
    }

#pragma unroll
    for (int i = 0; i < 4; ++i) {
        int cm = m0 + ty * 4 + i;
#pragma unroll
        for (int j = 0; j < 4; ++j) {
            int cn = n0 + tx * 4 + j;
            float v = acc[i][j] + bias[cn];
            if (EPI == 1) v = fmaxf(v, 0.f);
            if (EPI == 2) v += res[(size_t)cm * N + cn];
            out[(size_t)cm * N + cn] = v;
        }
    }
}

// ---------------------------------------------------------------------------
// Flash attention: one block per (64-query tile, head). 256 threads.
// qkv layout [L, 768]: q at col h*32, k at 256+h*32, v at 512+h*32.
// mask(q,k) = (u[q,k]>=0.1) + (q%S==k%S) + (q/S==k/S), S = 1<<sshift.
// ---------------------------------------------------------------------------
#define FQ 64
#define FK 64

__global__ __launch_bounds__(256) void flash_attn(const float* __restrict__ qkv,
                                                  const float* __restrict__ u,
                                                  float* __restrict__ o,
                                                  int L, int sshift) {
    __shared__ float qs[FQ][33];
    __shared__ float ks[FK][33];
    __shared__ float vs[FK][33];
    __shared__ float ps[FQ][65];
    __shared__ float rowm[FQ], rowfac[FQ], rowsum[FQ];

    const int h = blockIdx.y;
    const int q0 = blockIdx.x * FQ;
    const int t = threadIdx.x;
    const int smask = (1 << sshift) - 1;
    const float scale = 0.17677669529663687f;  // 32^-0.5

    // ---- load + scale Q tile: 64x32 floats ----
#pragma unroll
    for (int i = 0; i < 2; ++i) {
        int f4 = t + i * 256;                 // 0..511
        int r = f4 >> 3, c = (f4 & 7) * 4;
        float4 v = *(const float4*)&qkv[(size_t)(q0 + r) * 768 + h * 32 + c];
        qs[r][c + 0] = v.x * scale; qs[r][c + 1] = v.y * scale;
        qs[r][c + 2] = v.z * scale; qs[r][c + 3] = v.w * scale;
    }
    if (t < FQ) rowm[t] = -1e30f;

    // scores mapping: ty=t>>4 (0..15) -> rows ty*4+i; tx=t&15 -> cols tx+16*jj
    const int ty = t >> 4, tx = t & 15;
    int qrow[4], qp[4], qf[4];
#pragma unroll
    for (int i = 0; i < 4; ++i) {
        qrow[i] = q0 + ty * 4 + i;
        qp[i] = qrow[i] & smask;
        qf[i] = qrow[i] >> sshift;
    }

    // PV mapping: rr=t>>3 (0..31) -> rows {rr, rr+32}; j=t&7 -> dims j*4..+4
    const int rr = t >> 3, j = t & 7;
    float o0[4] = {}, o1[4] = {};
    float l0 = 0.f, l1 = 0.f;

    for (int k0 = 0; k0 < L; k0 += FK) {
        // ---- stage K and V tiles (64x32 each) ----
#pragma unroll
        for (int i = 0; i < 2; ++i) {
            int f4 = t + i * 256;
            int r = f4 >> 3, c = (f4 & 7) * 4;
            const float* kp_ = &qkv[(size_t)(k0 + r) * 768 + 256 + h * 32 + c];
            float4 kv = *(const float4*)kp_;
            ks[r][c + 0] = kv.x; ks[r][c + 1] = kv.y;
            ks[r][c + 2] = kv.z; ks[r][c + 3] = kv.w;
            float4 vv = *(const float4*)(kp_ + 256);
            vs[r][c + 0] = vv.x; vs[r][c + 1] = vv.y;
            vs[r][c + 2] = vv.z; vs[r][c + 3] = vv.w;
        }
        __syncthreads();

        // ---- scores: 4 rows x 4 cols per thread ----
        float acc[4][4] = {};
#pragma unroll
        for (int kk = 0; kk < 32; ++kk) {
            float a[4], b[4];
#pragma unroll
            for (int i = 0; i < 4; ++i) a[i] = qs[ty * 4 + i][kk];
#pragma unroll
            for (int jj = 0; jj < 4; ++jj) b[jj] = ks[tx + 16 * jj][kk];
#pragma unroll
            for (int i = 0; i < 4; ++i)
#pragma unroll
                for (int jj = 0; jj < 4; ++jj) acc[i][jj] += a[i] * b[jj];
        }
        // add mask
#pragma unroll
        for (int jj = 0; jj < 4; ++jj) {
            int kl = k0 + tx + 16 * jj;
            int kp2 = kl & smask, kf = kl >> sshift;
#pragma unroll
            for (int i = 0; i < 4; ++i) {
                float m = (u[(size_t)qrow[i] * L + kl] >= 0.1f ? 1.f : 0.f)
                        + (kp2 == qp[i] ? 1.f : 0.f)
                        + (kf == qf[i] ? 1.f : 0.f);
                acc[i][jj] += m;
            }
        }

        // ---- online softmax for the 4 owned rows ----
        float tmax[4], tsum[4];
#pragma unroll
        for (int i = 0; i < 4; ++i) {
            float mx = fmaxf(fmaxf(acc[i][0], acc[i][1]), fmaxf(acc[i][2], acc[i][3]));
#pragma unroll
            for (int w = 1; w < 16; w <<= 1) mx = fmaxf(mx, __shfl_xor(mx, w));
            tmax[i] = mx;
        }
#pragma unroll
        for (int i = 0; i < 4; ++i) {
            int r = ty * 4 + i;
            float oldm = rowm[r];
            float newm = fmaxf(oldm, tmax[i]);
            float s = 0.f;
#pragma unroll
            for (int jj = 0; jj < 4; ++jj) {
                float e = __expf(acc[i][jj] - newm);
                ps[r][tx + 16 * jj] = e;
                s += e;
            }
#pragma unroll
            for (int w = 1; w < 16; w <<= 1) s += __shfl_xor(s, w);
            tsum[i] = s;
            if (tx == 0) {
                rowm[r] = newm;
                rowfac[r] = __expf(oldm - newm);
                rowsum[r] = s;
            }
        }
        (void)tsum;
        __syncthreads();

        // ---- PV: o[r][d] accumulate ----
        float fac0 = rowfac[rr], fac1 = rowfac[rr + 32];
        l0 = l0 * fac0 + rowsum[rr];
        l1 = l1 * fac1 + rowsum[rr + 32];
#pragma unroll
        for (int dd = 0; dd < 4; ++dd) { o0[dd] *= fac0; o1[dd] *= fac1; }
#pragma unroll 8
        for (int k = 0; k < FK; ++k) {
            float p0 = ps[rr][k], p1 = ps[rr + 32][k];
            const float* vrow = &vs[k][j * 4];
#pragma unroll
            for (int dd = 0; dd < 4; ++dd) {
                float vv = vrow[dd];
                o0[dd] += p0 * vv;
                o1[dd] += p1 * vv;
            }
        }
        __syncthreads();
    }

    // ---- write out (normalize) ----
    float inv0 = 1.f / l0, inv1 = 1.f / l1;
    float4 w0, w1;
    w0.x = o0[0] * inv0; w0.y = o0[1] * inv0; w0.z = o0[2] * inv0; w0.w = o0[3] * inv0;
    w1.x = o1[0] * inv1; w1.y = o1[1] * inv1; w1.z = o1[2] * inv1; w1.w = o1[3] * inv1;
    *(float4*)&o[(size_t)(q0 + rr) * 256 + h * 32 + j * 4] = w0;
    *(float4*)&o[(size_t)(q0 + rr + 32) * 256 + h * 32 + j * 4] = w1;
}

// LayerNorm over C=256, one block per row
__global__ __launch_bounds__(256) void ln_kernel(const float* __restrict__ in,
                                                 const float* __restrict__ g,
                                                 const float* __restrict__ b,
                                                 float* __restrict__ out) {
    __shared__ float red[256];
    int row = blockIdx.x, t = threadIdx.x;
    float v = in[(size_t)row * 256 + t];
    red[t] = v;
    __syncthreads();
    for (int s = 128; s > 0; s >>= 1) {
        if (t < s) red[t] += red[t + s];
        __syncthreads();
    }
    float mean = red[0] * (1.f / 256.f);
    __syncthreads();
    float d = v - mean;
    red[t] = d * d;
    __syncthreads();
    for (int s = 128; s > 0; s >>= 1) {
        if (t < s) red[t] += red[t + s];
        __syncthreads();
    }
    float var = red[0] * (1.f / 256.f);
    out[(size_t)row * 256 + t] = d * rsqrtf(var + 1e-5f) * g[t] + b[t];
}

// ---------------------------------------------------------------------------

struct Params {
    const float *Wqkv, *bqkv, *Wo, *bo, *g1, *b1, *Wfc1, *bfc1, *Wfc2, *bfc2, *g2, *b2;
};

static void run_level(const float* f, const float* u, int S, int L,
                      float* out, float* ws, const Params& p, hipStream_t stream) {
    float* src  = ws;                 // 524288
    float* qkv  = ws + 524288;        // 1572864
    float* obuf = ws + 2097152;       // 524288
    float* t1   = ws + 2621440;       // 524288
    float* x    = ws + 3145728;       // 524288
    float* hbuf = ws + 3670016;       // 2097152

    int sshift = (S == 1024) ? 10 : 8;

    nchw_to_lc<<<L, 256, 0, stream>>>(f, src, S);
    gemm_kernel<0><<<dim3(768 / TILE, L / TILE), 256, 0, stream>>>(
        src, p.Wqkv, p.bqkv, nullptr, qkv, L, 768, 256);
    flash_attn<<<dim3(L / FQ, 8), 256, 0, stream>>>(qkv, u, obuf, L, sshift);
    gemm_kernel<2><<<dim3(256 / TILE, L / TILE), 256, 0, stream>>>(
        obuf, p.Wo, p.bo, src, t1, L, 256, 256);
    ln_kernel<<<L, 256, 0, stream>>>(t1, p.g1, p.b1, x);
    gemm_kernel<1><<<dim3(1024 / TILE, L / TILE), 256, 0, stream>>>(
        x, p.Wfc1, p.bfc1, nullptr, hbuf, L, 1024, 256);
    gemm_kernel<2><<<dim3(256 / TILE, L / TILE), 256, 0, stream>>>(
        hbuf, p.Wfc2, p.bfc2, x, t1, L, 256, 1024);
    ln_kernel<<<L, 256, 0, stream>>>(t1, p.g2, p.b2, obuf);
    lc_to_nchw<<<L, 256, 0, stream>>>(obuf, out, S);
}

extern "C" void kernel_launch(void* const* d_in, const int* in_sizes, int n_in,
                              void* d_out, int out_size, void* d_ws, size_t ws_size,
                              hipStream_t stream) {
    const float* f0 = (const float*)d_in[0];
    const float* f1 = (const float*)d_in[1];
    const float* f2 = (const float*)d_in[2];
    const float* f3 = (const float*)d_in[3];
    const float* u2 = (const float*)d_in[4];
    const float* u3 = (const float*)d_in[5];
    Params p;
    p.Wqkv = (const float*)d_in[6];  p.bqkv = (const float*)d_in[7];
    p.Wo   = (const float*)d_in[8];  p.bo   = (const float*)d_in[9];
    p.g1   = (const float*)d_in[10]; p.b1   = (const float*)d_in[11];
    p.Wfc1 = (const float*)d_in[12]; p.bfc1 = (const float*)d_in[13];
    p.Wfc2 = (const float*)d_in[14]; p.bfc2 = (const float*)d_in[15];
    p.g2   = (const float*)d_in[16]; p.b2   = (const float*)d_in[17];

    float* out = (float*)d_out;
    float* ws = (float*)d_ws;

    // f0, f1 pass through
    hipMemcpyAsync(out, f0, (size_t)3276800 * 4, hipMemcpyDeviceToDevice, stream);
    hipMemcpyAsync(out + 3276800, f1, (size_t)819200 * 4, hipMemcpyDeviceToDevice, stream);

    // level 2: N=2, S=1024, L=2048
    run_level(f2, u2, 1024, 2048, out + 4096000, ws, p, stream);
    // level 3: N=2, S=256, L=512
    run_level(f3, u3, 256, 512, out + 4620288, ws, p, stream);
}

// Round 3
// 394.939 us; speedup vs baseline: 3.2107x; 1.6262x over previous
//
#include <hip/hip_runtime.h>
#include <hip/hip_bf16.h>
#include <cstddef>

// ---------------------------------------------------------------------------
// sparse_attn: transformer encoder block on levels 2 & 3.
// Round 3: MFMA bf16 flash attention (S^T = K·Q^T trick, per-lane softmax).
// ---------------------------------------------------------------------------

typedef __attribute__((ext_vector_type(8))) short s16x8;   // 8 bf16 (4 VGPR)
typedef __attribute__((ext_vector_type(4))) short s16x4;   // 4 bf16 (b64)
typedef __attribute__((ext_vector_type(4))) float f32x4;
typedef __attribute__((ext_vector_type(2))) unsigned int u32x2;

#define TILE 64
#define BK 16

__device__ inline unsigned short f2bf(float x) {
    union { __hip_bfloat16 h; unsigned short u; } cv;
    cv.h = __float2bfloat16(x);
    return cv.u;
}

// NCHW (N=2) -> [L=N*S, C=256] row-major
__global__ __launch_bounds__(256) void nchw_to_lc(const float* __restrict__ f,
                                                  float* __restrict__ src,
                                                  int S) {
    int idx = blockIdx.x * 256 + threadIdx.x;
    int l = idx >> 8, c = idx & 255;
    int n = l / S, hw = l % S;
    src[idx] = f[((size_t)(n * 256 + c)) * S + hw];
}

// [L,C] -> NCHW (N=2)
__global__ __launch_bounds__(256) void lc_to_nchw(const float* __restrict__ y,
                                                  float* __restrict__ out,
                                                  int S) {
    int idx = blockIdx.x * 256 + threadIdx.x;
    int n = idx / (256 * S);
    int rem = idx - n * 256 * S;
    int c = rem / S;
    int hw = rem - c * S;
    out[idx] = y[((size_t)(n * S + hw)) * 256 + c];
}

// qkv fp32 [L,768] -> bf16 [L,768], q columns pre-scaled by 32^-0.5
__global__ __launch_bounds__(256) void cvt_qkv(const float* __restrict__ qkv,
                                               unsigned short* __restrict__ qkvb,
                                               int total4) {
    int i = blockIdx.x * 256 + threadIdx.x;
    if (i >= total4) return;
    f32x4 v = ((const f32x4*)qkv)[i];
    int col4 = i % 192;  // 768/4
    float sc = (col4 < 64) ? 0.17677669529663687f : 1.f;
    s16x4 r;
    r[0] = (short)f2bf(v[0] * sc);
    r[1] = (short)f2bf(v[1] * sc);
    r[2] = (short)f2bf(v[2] * sc);
    r[3] = (short)f2bf(v[3] * sc);
    ((s16x4*)qkvb)[i] = r;
}

// C[M,N] = A[M,K] @ W[N,K]^T + bias[N]  (+ optional relu / residual)  fp32
template <int EPI>
__global__ __launch_bounds__(256) void gemm_kernel(const float* __restrict__ A,
                                                   const float* __restrict__ W,
                                                   const float* __restrict__ bias,
                                                   const float* __restrict__ res,
                                                   float* __restrict__ out,
                                                   int M, int N, int K) {
    __shared__ float As[TILE][BK + 1];
    __shared__ float Ws[TILE][BK + 1];
    int tid = threadIdx.x;
    int tx = tid & 15, ty = tid >> 4;
    int m0 = blockIdx.y * TILE, n0 = blockIdx.x * TILE;
    int lrow = tid >> 2;
    int lcg = (tid & 3) * 4;
    float acc[4][4] = {};

    for (int k0 = 0; k0 < K; k0 += BK) {
        float4 av = *(const float4*)&A[(size_t)(m0 + lrow) * K + k0 + lcg];
        As[lrow][lcg + 0] = av.x; As[lrow][lcg + 1] = av.y;
        As[lrow][lcg + 2] = av.z; As[lrow][lcg + 3] = av.w;
        float4 wv = *(const float4*)&W[(size_t)(n0 + lrow) * K + k0 + lcg];
        Ws[lrow][lcg + 0] = wv.x; Ws[lrow][lcg + 1] = wv.y;
        Ws[lrow][lcg + 2] = wv.z; Ws[lrow][lcg + 3] = wv.w;
        __syncthreads();
#pragma unroll
        for (int kk = 0; kk < BK; ++kk) {
            float a[4], b[4];
#pragma unroll
            for (int i = 0; i < 4; ++i) a[i] = As[ty * 4 + i][kk];
#pragma unroll
            for (int j = 0; j < 4; ++j) b[j] = Ws[tx * 4 + j][kk];
#pragma unroll
            for (int i = 0; i < 4; ++i)
#pragma unroll
                for (int j = 0; j < 4; ++j) acc[i][j] += a[i] * b[j];
        }
        __syncthreads();
    }

#pragma unroll
    for (int i = 0; i < 4; ++i) {
        int cm = m0 + ty * 4 + i;
#pragma unroll
        for (int j = 0; j < 4; ++j) {
            int cn = n0 + tx * 4 + j;
            float v = acc[i][j] + bias[cn];
            if (EPI == 1) v = fmaxf(v, 0.f);
            if (EPI == 2) v += res[(size_t)cm * N + cn];
            out[(size_t)cm * N + cn] = v;
        }
    }
}

// ---------------------------------------------------------------------------
// MFMA flash attention.
// Block = (64-query tile, head), 4 waves, wave w owns q rows 16w..16w+15.
// S^T = mfma(K_frag, Q_frag): lane holds S[q = l&15][k = 16nt + 4g + reg].
// O^T = mfma(Vt_frag, P_frag): lane holds O[q = l&15][d = 16dt + 4g + reg].
// ---------------------------------------------------------------------------
#define QS 40   // qs row stride (ushort), 32 data + 8 pad
#define KS 40
#define VS 72   // vts row stride, 64 data + 8 pad
#define PS 80   // ps row stride, 64 data + 16 pad
#define OS 68   // os row stride (float)

__global__ __launch_bounds__(256) void flash_mfma(const unsigned short* __restrict__ qkvb,
                                                  const float* __restrict__ u,
                                                  float* __restrict__ o,
                                                  int L, int sshift) {
    __shared__ __align__(16) unsigned short qs[64 * QS];
    __shared__ __align__(16) unsigned short ks[2][64 * KS];
    __shared__ __align__(16) unsigned short vts[2][32 * VS];
    __shared__ __align__(16) char pso[64 * PS * 2];  // ps (bf16) / os (f32) alias
    unsigned short* ps = (unsigned short*)pso;
    float* os = (float*)pso;

    const int h = blockIdx.y;
    const int q0 = blockIdx.x * 64;
    const int t = threadIdx.x;
    const int w = t >> 6;     // wave 0..3
    const int l = t & 63;
    const int c = l & 15;     // q-col / A-row index
    const int g = l >> 4;     // 0..3
    const int smask = (1 << sshift) - 1;
    const int ntiles = L >> 6;

    const int srow = t >> 2;            // staging row 0..63
    const int sc8 = (t & 3) * 8;        // staging col (ushort)

    // ---- Q tile -> qs ----
    *(s16x8*)&qs[srow * QS + sc8] =
        *(const s16x8*)&qkvb[(size_t)(q0 + srow) * 768 + h * 32 + sc8];

    // ---- stage tile 0 ----
    {
        s16x8 kreg = *(const s16x8*)&qkvb[(size_t)srow * 768 + 256 + h * 32 + sc8];
        s16x8 vreg = *(const s16x8*)&qkvb[(size_t)srow * 768 + 512 + h * 32 + sc8];
        *(s16x8*)&ks[0][srow * KS + sc8] = kreg;
#pragma unroll
        for (int i = 0; i < 8; ++i)
            vts[0][(sc8 + i) * VS + srow] = (unsigned short)vreg[i];
    }
    __syncthreads();

    const s16x8 qf = *(const s16x8*)&qs[(16 * w + c) * QS + 8 * g];
    const int qg = q0 + 16 * w + c;          // global q row for this lane
    const int qp = qg & smask, qfr = qg >> sshift;

    f32x4 oacc0 = {0.f, 0.f, 0.f, 0.f};
    f32x4 oacc1 = {0.f, 0.f, 0.f, 0.f};
    float mold = -3e38f, lrun = 0.f;
    const f32x4 zc = {0.f, 0.f, 0.f, 0.f};

    for (int kt = 0; kt < ntiles; ++kt) {
        const int bb = kt & 1;
        const int k0 = kt << 6;
        const bool pf = (kt + 1 < ntiles);
        s16x8 kreg, vreg;
        if (pf) {
            size_t base = (size_t)(k0 + 64 + srow) * 768 + h * 32 + sc8;
            kreg = *(const s16x8*)&qkvb[base + 256];
            vreg = *(const s16x8*)&qkvb[base + 512];
        }

        // ---- S^T = K · Q^T : 4 MFMAs ----
        f32x4 sacc[4];
#pragma unroll
        for (int nt = 0; nt < 4; ++nt) {
            s16x8 kf = *(const s16x8*)&ks[bb][(16 * nt + c) * KS + 8 * g];
            sacc[nt] = __builtin_amdgcn_mfma_f32_16x16x32_bf16(kf, qf, zc, 0, 0, 0);
        }

        // ---- mask + per-lane online softmax (q = lane's c) ----
        const float* urow = &u[(size_t)qg * L + k0];
        float sv[4][4];
        float m = -3e38f;
#pragma unroll
        for (int nt = 0; nt < 4; ++nt) {
            f32x4 uv = *(const f32x4*)&urow[16 * nt + 4 * g];
#pragma unroll
            for (int r = 0; r < 4; ++r) {
                int kg = k0 + 16 * nt + 4 * g + r;
                float s = sacc[nt][r]
                        + (uv[r] >= 0.1f ? 1.f : 0.f)
                        + ((kg & smask) == qp ? 1.f : 0.f)
                        + ((kg >> sshift) == qfr ? 1.f : 0.f);
                sv[nt][r] = s;
                m = fmaxf(m, s);
            }
        }
        m = fmaxf(m, __shfl_xor(m, 16));
        m = fmaxf(m, __shfl_xor(m, 32));
        float newm = fmaxf(mold, m);
        float fac = __expf(mold - newm);
        mold = newm;

        float sum = 0.f;
#pragma unroll
        for (int nt = 0; nt < 4; ++nt) {
            float p0 = __expf(sv[nt][0] - newm);
            float p1 = __expf(sv[nt][1] - newm);
            float p2 = __expf(sv[nt][2] - newm);
            float p3 = __expf(sv[nt][3] - newm);
            sum += (p0 + p1) + (p2 + p3);
            u32x2 pk;
            pk[0] = ((unsigned)f2bf(p1) << 16) | f2bf(p0);
            pk[1] = ((unsigned)f2bf(p3) << 16) | f2bf(p2);
            *(u32x2*)&ps[(16 * w + c) * PS + 16 * nt + 4 * g] = pk;
        }
        sum += __shfl_xor(sum, 16);
        sum += __shfl_xor(sum, 32);
        lrun = lrun * fac + sum;
        oacc0 *= fac;
        oacc1 *= fac;

        // ---- O^T += V^T · P^T : 4 MFMAs ----
#pragma unroll
        for (int kc = 0; kc < 2; ++kc) {
            s16x8 pfr = *(const s16x8*)&ps[(16 * w + c) * PS + 32 * kc + 8 * g];
            s16x8 vf0 = *(const s16x8*)&vts[bb][(c) * VS + 32 * kc + 8 * g];
            s16x8 vf1 = *(const s16x8*)&vts[bb][(16 + c) * VS + 32 * kc + 8 * g];
            oacc0 = __builtin_amdgcn_mfma_f32_16x16x32_bf16(vf0, pfr, oacc0, 0, 0, 0);
            oacc1 = __builtin_amdgcn_mfma_f32_16x16x32_bf16(vf1, pfr, oacc1, 0, 0, 0);
        }

        __syncthreads();
        if (pf) {
            int nb = bb ^ 1;
            *(s16x8*)&ks[nb][srow * KS + sc8] = kreg;
#pragma unroll
            for (int i = 0; i < 8; ++i)
                vts[nb][(sc8 + i) * VS + srow] = (unsigned short)vreg[i];
        }
        __syncthreads();
    }

    // ---- normalize, transpose through LDS, write O[q][d] coalesced ----
    float inv = 1.f / lrun;
#pragma unroll
    for (int r = 0; r < 4; ++r) {
        os[(4 * g + r) * OS + 16 * w + c] = oacc0[r] * inv;
        os[(16 + 4 * g + r) * OS + 16 * w + c] = oacc1[r] * inv;
    }
    __syncthreads();
    {
        int r = t >> 2, d0 = (t & 3) * 8;
        float vals[8];
#pragma unroll
        for (int i = 0; i < 8; ++i) vals[i] = os[(d0 + i) * OS + r];
        f32x4 w0 = {vals[0], vals[1], vals[2], vals[3]};
        f32x4 w1 = {vals[4], vals[5], vals[6], vals[7]};
        *(f32x4*)&o[(size_t)(q0 + r) * 256 + h * 32 + d0] = w0;
        *(f32x4*)&o[(size_t)(q0 + r) * 256 + h * 32 + d0 + 4] = w1;
    }
}

// LayerNorm over C=256, one block per row
__global__ __launch_bounds__(256) void ln_kernel(const float* __restrict__ in,
                                                 const float* __restrict__ g,
                                                 const float* __restrict__ b,
                                                 float* __restrict__ out) {
    __shared__ float red[256];
    int row = blockIdx.x, t = threadIdx.x;
    float v = in[(size_t)row * 256 + t];
    red[t] = v;
    __syncthreads();
    for (int s = 128; s > 0; s >>= 1) {
        if (t < s) red[t] += red[t + s];
        __syncthreads();
    }
    float mean = red[0] * (1.f / 256.f);
    __syncthreads();
    float d = v - mean;
    red[t] = d * d;
    __syncthreads();
    for (int s = 128; s > 0; s >>= 1) {
        if (t < s) red[t] += red[t + s];
        __syncthreads();
    }
    float var = red[0] * (1.f / 256.f);
    out[(size_t)row * 256 + t] = d * rsqrtf(var + 1e-5f) * g[t] + b[t];
}

// ---------------------------------------------------------------------------

struct Params {
    const float *Wqkv, *bqkv, *Wo, *bo, *g1, *b1, *Wfc1, *bfc1, *Wfc2, *bfc2, *g2, *b2;
};

static void run_level(const float* f, const float* u, int S, int L,
                      float* out, float* ws, const Params& p, hipStream_t stream) {
    float* src  = ws;                 // 524288
    float* qkv  = ws + 524288;        // 1572864
    float* obuf = ws + 2097152;       // 524288
    float* t1   = ws + 2621440;       // 524288
    float* x    = ws + 3145728;       // 524288
    float* hbuf = ws + 3670016;       // 2097152 (also aliases qkvb bf16)
    unsigned short* qkvb = (unsigned short*)hbuf;

    int sshift = (S == 1024) ? 10 : 8;

    nchw_to_lc<<<L, 256, 0, stream>>>(f, src, S);
    gemm_kernel<0><<<dim3(768 / TILE, L / TILE), 256, 0, stream>>>(
        src, p.Wqkv, p.bqkv, nullptr, qkv, L, 768, 256);
    cvt_qkv<<<(L * 192) / 256, 256, 0, stream>>>(qkv, qkvb, L * 192);
    flash_mfma<<<dim3(L / 64, 8), 256, 0, stream>>>(qkvb, u, obuf, L, sshift);
    gemm_kernel<2><<<dim3(256 / TILE, L / TILE), 256, 0, stream>>>(
        obuf, p.Wo, p.bo, src, t1, L, 256, 256);
    ln_kernel<<<L, 256, 0, stream>>>(t1, p.g1, p.b1, x);
    gemm_kernel<1><<<dim3(1024 / TILE, L / TILE), 256, 0, stream>>>(
        x, p.Wfc1, p.bfc1, nullptr, hbuf, L, 1024, 256);
    gemm_kernel<2><<<dim3(256 / TILE, L / TILE), 256, 0, stream>>>(
        hbuf, p.Wfc2, p.bfc2, x, t1, L, 256, 1024);
    ln_kernel<<<L, 256, 0, stream>>>(t1, p.g2, p.b2, obuf);
    lc_to_nchw<<<L, 256, 0, stream>>>(obuf, out, S);
}

extern "C" void kernel_launch(void* const* d_in, const int* in_sizes, int n_in,
                              void* d_out, int out_size, void* d_ws, size_t ws_size,
                              hipStream_t stream) {
    const float* f0 = (const float*)d_in[0];
    const float* f1 = (const float*)d_in[1];
    const float* f2 = (const float*)d_in[2];
    const float* f3 = (const float*)d_in[3];
    const float* u2 = (const float*)d_in[4];
    const float* u3 = (const float*)d_in[5];
    Params p;
    p.Wqkv = (const float*)d_in[6];  p.bqkv = (const float*)d_in[7];
    p.Wo   = (const float*)d_in[8];  p.bo   = (const float*)d_in[9];
    p.g1   = (const float*)d_in[10]; p.b1   = (const float*)d_in[11];
    p.Wfc1 = (const float*)d_in[12]; p.bfc1 = (const float*)d_in[13];
    p.Wfc2 = (const float*)d_in[14]; p.bfc2 = (const float*)d_in[15];
    p.g2   = (const float*)d_in[16]; p.b2   = (const float*)d_in[17];

    float* out = (float*)d_out;
    float* ws = (float*)d_ws;

    hipMemcpyAsync(out, f0, (size_t)3276800 * 4, hipMemcpyDeviceToDevice, stream);
    hipMemcpyAsync(out + 3276800, f1, (size_t)819200 * 4, hipMemcpyDeviceToDevice, stream);

    run_level(f2, u2, 1024, 2048, out + 4096000, ws, p, stream);
    run_level(f3, u3, 256, 512, out + 4620288, ws, p, stream);
}

// Round 4
// 165.766 us; speedup vs baseline: 7.6495x; 2.3825x over previous
//
#include <hip/hip_runtime.h>
#include <hip/hip_bf16.h>
#include <cstddef>

// ---------------------------------------------------------------------------
// sparse_attn: transformer encoder block on levels 2 & 3.
// Round 4: all GEMMs -> bf16 MFMA (fused epilogues), bf16 dataflow end-to-end.
// ---------------------------------------------------------------------------

typedef __attribute__((ext_vector_type(8))) short s16x8;   // 8 bf16 (4 VGPR)
typedef __attribute__((ext_vector_type(4))) short s16x4;
typedef __attribute__((ext_vector_type(4))) float f32x4;
typedef __attribute__((ext_vector_type(2))) unsigned int u32x2;
typedef unsigned short ushort_t;

__device__ inline unsigned short f2bf(float x) {
    union { __hip_bfloat16 h; unsigned short u; } cv;
    cv.h = __float2bfloat16(x);
    return cv.u;
}

// fp32 -> bf16 weight convert (n4 = count of float4)
__global__ __launch_bounds__(256) void cvt_w(const float* __restrict__ in,
                                             ushort_t* __restrict__ out, int n4) {
    int i = blockIdx.x * 256 + threadIdx.x;
    if (i >= n4) return;
    f32x4 v = ((const f32x4*)in)[i];
    s16x4 r;
    r[0] = (short)f2bf(v[0]); r[1] = (short)f2bf(v[1]);
    r[2] = (short)f2bf(v[2]); r[3] = (short)f2bf(v[3]);
    ((s16x4*)out)[i] = r;
}

// NCHW (N=2) -> [L,256] fp32 + bf16
__global__ __launch_bounds__(256) void nchw_to_lc2(const float* __restrict__ f,
                                                   float* __restrict__ srcf,
                                                   ushort_t* __restrict__ srcb,
                                                   int S) {
    int idx = blockIdx.x * 256 + threadIdx.x;
    int l = idx >> 8, c = idx & 255;
    int n = l / S, hw = l % S;
    float v = f[((size_t)(n * 256 + c)) * S + hw];
    srcf[idx] = v;
    srcb[idx] = f2bf(v);
}

// [L,C] -> NCHW (N=2)
__global__ __launch_bounds__(256) void lc_to_nchw(const float* __restrict__ y,
                                                  float* __restrict__ out,
                                                  int S) {
    int idx = blockIdx.x * 256 + threadIdx.x;
    int n = idx / (256 * S);
    int rem = idx - n * 256 * S;
    int c = rem / S;
    int hw = rem - c * S;
    out[idx] = y[((size_t)(n * S + hw)) * 256 + c];
}

// ---------------------------------------------------------------------------
// bf16 MFMA GEMM: out[M,N] = A[M,K] @ W[N,K]^T + bias  (+ epilogue)
// Tile 64x32, 4 waves (wave w: rows 16w..16w+15, all 32 cols), K-step 64.
// EPI: 0=bias, 1=bias+relu, 2=bias+res(f32), 3=bias then q-scale (n<256)
// OUTBF: 1 -> bf16 out, 0 -> f32 out
// ---------------------------------------------------------------------------
#define ASTR 72   // LDS row stride (ushorts): 64 data + 8 pad (144 B)

template <int EPI, int OUTBF>
__global__ __launch_bounds__(256) void gemm_mfma(const ushort_t* __restrict__ A,
                                                 const ushort_t* __restrict__ W,
                                                 const float* __restrict__ bias,
                                                 const float* __restrict__ res,
                                                 void* __restrict__ outv,
                                                 int M, int N, int K) {
    __shared__ __align__(16) ushort_t As[2][64 * ASTR];
    __shared__ __align__(16) ushort_t Ws[2][32 * ASTR];

    const int t = threadIdx.x;
    const int w = t >> 6, l = t & 63;
    const int c = l & 15, g = l >> 4;
    const int m0 = blockIdx.y * 64, n0 = blockIdx.x * 32;
    const int srow = t >> 3;          // 0..31
    const int cg8 = (t & 7) * 8;      // k-offset within 64

    const ushort_t* Aip = &A[(size_t)(m0 + srow) * K + cg8];
    const ushort_t* Aip2 = &A[(size_t)(m0 + 32 + srow) * K + cg8];
    const ushort_t* Wip = &W[(size_t)(n0 + srow) * K + cg8];

    // prologue: stage K-step 0
    s16x8 ra0 = *(const s16x8*)Aip;
    s16x8 ra1 = *(const s16x8*)Aip2;
    s16x8 rw = *(const s16x8*)Wip;
    *(s16x8*)&As[0][srow * ASTR + cg8] = ra0;
    *(s16x8*)&As[0][(32 + srow) * ASTR + cg8] = ra1;
    *(s16x8*)&Ws[0][srow * ASTR + cg8] = rw;
    __syncthreads();

    f32x4 acc[2] = {{0.f, 0.f, 0.f, 0.f}, {0.f, 0.f, 0.f, 0.f}};
    const int nsteps = K >> 6;

    for (int ks = 0; ks < nsteps; ++ks) {
        const int b = ks & 1;
        const bool pf = (ks + 1 < nsteps);
        if (pf) {
            int ko = (ks + 1) << 6;
            ra0 = *(const s16x8*)(Aip + ko);
            ra1 = *(const s16x8*)(Aip2 + ko);
            rw = *(const s16x8*)(Wip + ko);
        }
#pragma unroll
        for (int kt = 0; kt < 2; ++kt) {
            s16x8 af = *(const s16x8*)&As[b][(16 * w + c) * ASTR + kt * 32 + 8 * g];
            s16x8 wf0 = *(const s16x8*)&Ws[b][c * ASTR + kt * 32 + 8 * g];
            s16x8 wf1 = *(const s16x8*)&Ws[b][(16 + c) * ASTR + kt * 32 + 8 * g];
            acc[0] = __builtin_amdgcn_mfma_f32_16x16x32_bf16(af, wf0, acc[0], 0, 0, 0);
            acc[1] = __builtin_amdgcn_mfma_f32_16x16x32_bf16(af, wf1, acc[1], 0, 0, 0);
        }
        if (pf) {
            int nb = b ^ 1;
            *(s16x8*)&As[nb][srow * ASTR + cg8] = ra0;
            *(s16x8*)&As[nb][(32 + srow) * ASTR + cg8] = ra1;
            *(s16x8*)&Ws[nb][srow * ASTR + cg8] = rw;
        }
        __syncthreads();
    }

    // epilogue: lane l, reg r -> out[m0 + 16w + 4g + r][n0 + 16nt + c]
#pragma unroll
    for (int nt = 0; nt < 2; ++nt) {
        int n = n0 + 16 * nt + c;
        float bv = bias[n];
        float sc = 1.f;
        if (EPI == 3) sc = (n < 256) ? 0.17677669529663687f : 1.f;
#pragma unroll
        for (int r = 0; r < 4; ++r) {
            int m = m0 + 16 * w + 4 * g + r;
            float v = acc[nt][r] + bv;
            if (EPI == 1) v = fmaxf(v, 0.f);
            if (EPI == 2) v += res[(size_t)m * N + n];
            if (EPI == 3) v *= sc;
            if (OUTBF) ((ushort_t*)outv)[(size_t)m * N + n] = f2bf(v);
            else ((float*)outv)[(size_t)m * N + n] = v;
        }
    }
}

// ---------------------------------------------------------------------------
// MFMA flash attention (unchanged core; O output now bf16).
// ---------------------------------------------------------------------------
#define QS 40
#define KS 40
#define VS 72
#define PS 80
#define OS 68

__global__ __launch_bounds__(256) void flash_mfma(const ushort_t* __restrict__ qkvb,
                                                  const float* __restrict__ u,
                                                  ushort_t* __restrict__ o,
                                                  int L, int sshift) {
    __shared__ __align__(16) ushort_t qs[64 * QS];
    __shared__ __align__(16) ushort_t ks[2][64 * KS];
    __shared__ __align__(16) ushort_t vts[2][32 * VS];
    __shared__ __align__(16) char pso[64 * PS * 2];
    ushort_t* ps = (ushort_t*)pso;
    float* os = (float*)pso;

    const int h = blockIdx.y;
    const int q0 = blockIdx.x * 64;
    const int t = threadIdx.x;
    const int w = t >> 6;
    const int l = t & 63;
    const int c = l & 15;
    const int g = l >> 4;
    const int smask = (1 << sshift) - 1;
    const int ntiles = L >> 6;

    const int srow = t >> 2;
    const int sc8 = (t & 3) * 8;

    *(s16x8*)&qs[srow * QS + sc8] =
        *(const s16x8*)&qkvb[(size_t)(q0 + srow) * 768 + h * 32 + sc8];

    {
        s16x8 kreg = *(const s16x8*)&qkvb[(size_t)srow * 768 + 256 + h * 32 + sc8];
        s16x8 vreg = *(const s16x8*)&qkvb[(size_t)srow * 768 + 512 + h * 32 + sc8];
        *(s16x8*)&ks[0][srow * KS + sc8] = kreg;
#pragma unroll
        for (int i = 0; i < 8; ++i)
            vts[0][(sc8 + i) * VS + srow] = (ushort_t)vreg[i];
    }
    __syncthreads();

    const s16x8 qf = *(const s16x8*)&qs[(16 * w + c) * QS + 8 * g];
    const int qg = q0 + 16 * w + c;
    const int qp = qg & smask, qfr = qg >> sshift;

    f32x4 oacc0 = {0.f, 0.f, 0.f, 0.f};
    f32x4 oacc1 = {0.f, 0.f, 0.f, 0.f};
    float mold = -3e38f, lrun = 0.f;
    const f32x4 zc = {0.f, 0.f, 0.f, 0.f};

    for (int kt = 0; kt < ntiles; ++kt) {
        const int bb = kt & 1;
        const int k0 = kt << 6;
        const bool pf = (kt + 1 < ntiles);
        s16x8 kreg, vreg;
        if (pf) {
            size_t base = (size_t)(k0 + 64 + srow) * 768 + h * 32 + sc8;
            kreg = *(const s16x8*)&qkvb[base + 256];
            vreg = *(const s16x8*)&qkvb[base + 512];
        }

        f32x4 sacc[4];
#pragma unroll
        for (int nt = 0; nt < 4; ++nt) {
            s16x8 kf = *(const s16x8*)&ks[bb][(16 * nt + c) * KS + 8 * g];
            sacc[nt] = __builtin_amdgcn_mfma_f32_16x16x32_bf16(kf, qf, zc, 0, 0, 0);
        }

        const float* urow = &u[(size_t)qg * L + k0];
        float sv[4][4];
        float m = -3e38f;
#pragma unroll
        for (int nt = 0; nt < 4; ++nt) {
            f32x4 uv = *(const f32x4*)&urow[16 * nt + 4 * g];
#pragma unroll
            for (int r = 0; r < 4; ++r) {
                int kg = k0 + 16 * nt + 4 * g + r;
                float s = sacc[nt][r]
                        + (uv[r] >= 0.1f ? 1.f : 0.f)
                        + ((kg & smask) == qp ? 1.f : 0.f)
                        + ((kg >> sshift) == qfr ? 1.f : 0.f);
                sv[nt][r] = s;
                m = fmaxf(m, s);
            }
        }
        m = fmaxf(m, __shfl_xor(m, 16));
        m = fmaxf(m, __shfl_xor(m, 32));
        float newm = fmaxf(mold, m);
        float fac = __expf(mold - newm);
        mold = newm;

        float sum = 0.f;
#pragma unroll
        for (int nt = 0; nt < 4; ++nt) {
            float p0 = __expf(sv[nt][0] - newm);
            float p1 = __expf(sv[nt][1] - newm);
            float p2 = __expf(sv[nt][2] - newm);
            float p3 = __expf(sv[nt][3] - newm);
            sum += (p0 + p1) + (p2 + p3);
            u32x2 pk;
            pk[0] = ((unsigned)f2bf(p1) << 16) | f2bf(p0);
            pk[1] = ((unsigned)f2bf(p3) << 16) | f2bf(p2);
            *(u32x2*)&ps[(16 * w + c) * PS + 16 * nt + 4 * g] = pk;
        }
        sum += __shfl_xor(sum, 16);
        sum += __shfl_xor(sum, 32);
        lrun = lrun * fac + sum;
        oacc0 *= fac;
        oacc1 *= fac;

#pragma unroll
        for (int kc = 0; kc < 2; ++kc) {
            s16x8 pfr = *(const s16x8*)&ps[(16 * w + c) * PS + 32 * kc + 8 * g];
            s16x8 vf0 = *(const s16x8*)&vts[bb][c * VS + 32 * kc + 8 * g];
            s16x8 vf1 = *(const s16x8*)&vts[bb][(16 + c) * VS + 32 * kc + 8 * g];
            oacc0 = __builtin_amdgcn_mfma_f32_16x16x32_bf16(vf0, pfr, oacc0, 0, 0, 0);
            oacc1 = __builtin_amdgcn_mfma_f32_16x16x32_bf16(vf1, pfr, oacc1, 0, 0, 0);
        }

        __syncthreads();
        if (pf) {
            int nb = bb ^ 1;
            *(s16x8*)&ks[nb][srow * KS + sc8] = kreg;
#pragma unroll
            for (int i = 0; i < 8; ++i)
                vts[nb][(sc8 + i) * VS + srow] = (ushort_t)vreg[i];
        }
        __syncthreads();
    }

    float inv = 1.f / lrun;
#pragma unroll
    for (int r = 0; r < 4; ++r) {
        os[(4 * g + r) * OS + 16 * w + c] = oacc0[r] * inv;
        os[(16 + 4 * g + r) * OS + 16 * w + c] = oacc1[r] * inv;
    }
    __syncthreads();
    {
        int r = t >> 2, d0 = (t & 3) * 8;
        s16x8 pk;
#pragma unroll
        for (int i = 0; i < 8; ++i) pk[i] = (short)f2bf(os[(d0 + i) * OS + r]);
        *(s16x8*)&o[(size_t)(q0 + r) * 256 + h * 32 + d0] = pk;
    }
}

// LayerNorm over C=256, one block per row; optional bf16 copy of output
template <int WB>
__global__ __launch_bounds__(256) void ln_kernel(const float* __restrict__ in,
                                                 const float* __restrict__ g,
                                                 const float* __restrict__ b,
                                                 float* __restrict__ outf,
                                                 ushort_t* __restrict__ outb) {
    __shared__ float red[256];
    int row = blockIdx.x, t = threadIdx.x;
    float v = in[(size_t)row * 256 + t];
    red[t] = v;
    __syncthreads();
    for (int s = 128; s > 0; s >>= 1) {
        if (t < s) red[t] += red[t + s];
        __syncthreads();
    }
    float mean = red[0] * (1.f / 256.f);
    __syncthreads();
    float d = v - mean;
    red[t] = d * d;
    __syncthreads();
    for (int s = 128; s > 0; s >>= 1) {
        if (t < s) red[t] += red[t + s];
        __syncthreads();
    }
    float var = red[0] * (1.f / 256.f);
    float r = d * rsqrtf(var + 1e-5f) * g[t] + b[t];
    outf[(size_t)row * 256 + t] = r;
    if (WB) outb[(size_t)row * 256 + t] = f2bf(r);
}

// ---------------------------------------------------------------------------

struct Params {
    const float *Wqkv, *bqkv, *Wo, *bo, *g1, *b1, *Wfc1, *bfc1, *Wfc2, *bfc2, *g2, *b2;
};

struct WBf {
    ushort_t *wqkv, *wo, *wfc1, *wfc2;
};

static void run_level(const float* f, const float* u, int S, int L,
                      float* out, float* sc, const WBf& wb, const Params& p,
                      hipStream_t stream) {
    float* src_f32 = sc;                              // L*256 f32
    ushort_t* src_bf = (ushort_t*)(sc + 524288);      // L*256 bf16
    ushort_t* qkvb = (ushort_t*)(sc + 786432);        // L*768 bf16
    ushort_t* obuf_bf = (ushort_t*)(sc + 1572864);    // L*256 bf16
    float* t1 = sc + 1835008;                         // L*256 f32
    float* x_f32 = sc + 2359296;                      // L*256 f32
    ushort_t* x_bf = (ushort_t*)(sc + 2883584);       // L*256 bf16
    ushort_t* h_bf = (ushort_t*)(sc + 3145728);       // L*1024 bf16
    float* y = src_f32;                               // reuse after residual 1

    int sshift = (S == 1024) ? 10 : 8;

    nchw_to_lc2<<<L, 256, 0, stream>>>(f, src_f32, src_bf, S);
    gemm_mfma<3, 1><<<dim3(768 / 32, L / 64), 256, 0, stream>>>(
        src_bf, wb.wqkv, p.bqkv, nullptr, qkvb, L, 768, 256);
    flash_mfma<<<dim3(L / 64, 8), 256, 0, stream>>>(qkvb, u, obuf_bf, L, sshift);
    gemm_mfma<2, 0><<<dim3(256 / 32, L / 64), 256, 0, stream>>>(
        obuf_bf, wb.wo, p.bo, src_f32, t1, L, 256, 256);
    ln_kernel<1><<<L, 256, 0, stream>>>(t1, p.g1, p.b1, x_f32, x_bf);
    gemm_mfma<1, 1><<<dim3(1024 / 32, L / 64), 256, 0, stream>>>(
        x_bf, wb.wfc1, p.bfc1, nullptr, h_bf, L, 1024, 256);
    gemm_mfma<2, 0><<<dim3(256 / 32, L / 64), 256, 0, stream>>>(
        h_bf, wb.wfc2, p.bfc2, x_f32, t1, L, 256, 1024);
    ln_kernel<0><<<L, 256, 0, stream>>>(t1, p.g2, p.b2, y, nullptr);
    lc_to_nchw<<<L, 256, 0, stream>>>(y, out, S);
}

extern "C" void kernel_launch(void* const* d_in, const int* in_sizes, int n_in,
                              void* d_out, int out_size, void* d_ws, size_t ws_size,
                              hipStream_t stream) {
    const float* f0 = (const float*)d_in[0];
    const float* f1 = (const float*)d_in[1];
    const float* f2 = (const float*)d_in[2];
    const float* f3 = (const float*)d_in[3];
    const float* u2 = (const float*)d_in[4];
    const float* u3 = (const float*)d_in[5];
    Params p;
    p.Wqkv = (const float*)d_in[6];  p.bqkv = (const float*)d_in[7];
    p.Wo   = (const float*)d_in[8];  p.bo   = (const float*)d_in[9];
    p.g1   = (const float*)d_in[10]; p.b1   = (const float*)d_in[11];
    p.Wfc1 = (const float*)d_in[12]; p.bfc1 = (const float*)d_in[13];
    p.Wfc2 = (const float*)d_in[14]; p.bfc2 = (const float*)d_in[15];
    p.g2   = (const float*)d_in[16]; p.b2   = (const float*)d_in[17];

    float* out = (float*)d_out;
    float* ws = (float*)d_ws;

    // bf16 weights at the head of ws
    WBf wb;
    wb.wqkv = (ushort_t*)ws;             // 196608 us
    wb.wo   = (ushort_t*)(ws + 98304);   // 65536 us
    wb.wfc1 = (ushort_t*)(ws + 131072);  // 262144 us
    wb.wfc2 = (ushort_t*)(ws + 262144);  // 262144 us
    float* scratch = ws + 393216;

    cvt_w<<<192, 256, 0, stream>>>(p.Wqkv, wb.wqkv, 49152);
    cvt_w<<<64, 256, 0, stream>>>(p.Wo, wb.wo, 16384);
    cvt_w<<<256, 256, 0, stream>>>(p.Wfc1, wb.wfc1, 65536);
    cvt_w<<<256, 256, 0, stream>>>(p.Wfc2, wb.wfc2, 65536);

    // f0, f1 pass through
    hipMemcpyAsync(out, f0, (size_t)3276800 * 4, hipMemcpyDeviceToDevice, stream);
    hipMemcpyAsync(out + 3276800, f1, (size_t)819200 * 4, hipMemcpyDeviceToDevice, stream);

    run_level(f2, u2, 1024, 2048, out + 4096000, scratch, wb, p, stream);
    run_level(f3, u3, 256, 512, out + 4620288, scratch, wb, p, stream);
}

// Round 5
// 100.219 us; speedup vs baseline: 12.6525x; 1.6540x over previous
//
#include <hip/hip_runtime.h>
#include <hip/hip_bf16.h>
#include <cstddef>

// ---------------------------------------------------------------------------
// sparse_attn: transformer encoder block on levels 2 & 3.
// Round 5: split-KV flash (4x blocks), both levels batched into one pipeline.
// Rows 0..2047 = level2 (S=1024), rows 2048..2559 = level3 (S=256). R=2560.
// ---------------------------------------------------------------------------

typedef __attribute__((ext_vector_type(8))) short s16x8;
typedef __attribute__((ext_vector_type(4))) short s16x4;
typedef __attribute__((ext_vector_type(4))) float f32x4;
typedef __attribute__((ext_vector_type(2))) unsigned int u32x2;
typedef unsigned short ushort_t;

#define RTOT 2560

__device__ inline unsigned short f2bf(float x) {
    union { __hip_bfloat16 h; unsigned short u; } cv;
    cv.h = __float2bfloat16(x);
    return cv.u;
}

// all 4 weight matrices fp32 -> bf16 in one launch (196608 float4s)
__global__ __launch_bounds__(256) void cvt_all(const float* __restrict__ wqkv,
                                               const float* __restrict__ wo,
                                               const float* __restrict__ wfc1,
                                               const float* __restrict__ wfc2,
                                               ushort_t* __restrict__ o1,
                                               ushort_t* __restrict__ o2,
                                               ushort_t* __restrict__ o3,
                                               ushort_t* __restrict__ o4) {
    int i = blockIdx.x * 256 + threadIdx.x;
    const float* src; ushort_t* dst; int li;
    if (i < 49152)       { src = wqkv; dst = o1; li = i; }
    else if (i < 65536)  { src = wo;   dst = o2; li = i - 49152; }
    else if (i < 131072) { src = wfc1; dst = o3; li = i - 65536; }
    else                 { src = wfc2; dst = o4; li = i - 131072; }
    f32x4 v = ((const f32x4*)src)[li];
    s16x4 r;
    r[0] = (short)f2bf(v[0]); r[1] = (short)f2bf(v[1]);
    r[2] = (short)f2bf(v[2]); r[3] = (short)f2bf(v[3]);
    ((s16x4*)dst)[li] = r;
}

// f2 (2,256,32,32) + f3 (2,256,16,16) -> combined [2560,256] fp32 + bf16
__global__ __launch_bounds__(256) void nchw_in(const float* __restrict__ f2,
                                               const float* __restrict__ f3,
                                               float* __restrict__ srcf,
                                               ushort_t* __restrict__ srcb) {
    int idx = blockIdx.x * 256 + threadIdx.x;   // over 2560*256
    int r = idx >> 8, c = idx & 255;
    float v;
    if (r < 2048) {
        int n = r >> 10, hw = r & 1023;
        v = f2[(size_t)((n * 256 + c) << 10) + hw];
    } else {
        int rl = r - 2048;
        int n = rl >> 8, hw = rl & 255;
        v = f3[(size_t)((n * 256 + c) << 8) + hw];
    }
    srcf[idx] = v;
    srcb[idx] = f2bf(v);
}

// combined [2560,256] -> out2 (2,256,32,32) and out3 (2,256,16,16)
__global__ __launch_bounds__(256) void lc_out(const float* __restrict__ y,
                                              float* __restrict__ out2,
                                              float* __restrict__ out3) {
    int idx = blockIdx.x * 256 + threadIdx.x;   // over 655360
    if (idx < 524288) {
        int n = idx >> 18;                       // /(256*1024)
        int rem = idx & 262143;
        int c = rem >> 10, hw = rem & 1023;
        out2[idx] = y[(size_t)(n * 1024 + hw) * 256 + c];
    } else {
        int li = idx - 524288;
        int n = li >> 16;                        // /(256*256)
        int rem = li & 65535;
        int c = rem >> 8, hw = rem & 255;
        out3[li] = y[(size_t)(2048 + n * 256 + hw) * 256 + c];
    }
}

// ---------------------------------------------------------------------------
// bf16 MFMA GEMM, tile 32x32, 128 threads (2 waves), K-step 64, dbuf LDS.
// EPI: 0=bias, 1=bias+relu, 2=bias+res(f32), 3=bias then q-scale (n<256)
// ---------------------------------------------------------------------------
#define ASTR 72

template <int EPI, int OUTBF>
__global__ __launch_bounds__(128) void gemm32(const ushort_t* __restrict__ A,
                                              const ushort_t* __restrict__ W,
                                              const float* __restrict__ bias,
                                              const float* __restrict__ res,
                                              void* __restrict__ outv,
                                              int M, int N, int K) {
    __shared__ __align__(16) ushort_t As[2][32 * ASTR];
    __shared__ __align__(16) ushort_t Ws[2][32 * ASTR];

    const int t = threadIdx.x;
    const int w = t >> 6, l = t & 63;
    const int c = l & 15, g = l >> 4;
    const int m0 = blockIdx.y * 32, n0 = blockIdx.x * 32;
    const int srow = t >> 3;          // 0..15
    const int cg8 = (t & 7) * 8;      // k offset 0..56

    const ushort_t* Aip0 = &A[(size_t)(m0 + srow) * K + cg8];
    const ushort_t* Aip1 = &A[(size_t)(m0 + 16 + srow) * K + cg8];
    const ushort_t* Wip0 = &W[(size_t)(n0 + srow) * K + cg8];
    const ushort_t* Wip1 = &W[(size_t)(n0 + 16 + srow) * K + cg8];

    s16x8 ra0 = *(const s16x8*)Aip0;
    s16x8 ra1 = *(const s16x8*)Aip1;
    s16x8 rw0 = *(const s16x8*)Wip0;
    s16x8 rw1 = *(const s16x8*)Wip1;
    *(s16x8*)&As[0][srow * ASTR + cg8] = ra0;
    *(s16x8*)&As[0][(16 + srow) * ASTR + cg8] = ra1;
    *(s16x8*)&Ws[0][srow * ASTR + cg8] = rw0;
    *(s16x8*)&Ws[0][(16 + srow) * ASTR + cg8] = rw1;
    __syncthreads();

    f32x4 acc[2] = {{0.f, 0.f, 0.f, 0.f}, {0.f, 0.f, 0.f, 0.f}};
    const int nsteps = K >> 6;

    for (int ks = 0; ks < nsteps; ++ks) {
        const int b = ks & 1;
        const bool pf = (ks + 1 < nsteps);
        if (pf) {
            int ko = (ks + 1) << 6;
            ra0 = *(const s16x8*)(Aip0 + ko);
            ra1 = *(const s16x8*)(Aip1 + ko);
            rw0 = *(const s16x8*)(Wip0 + ko);
            rw1 = *(const s16x8*)(Wip1 + ko);
        }
#pragma unroll
        for (int kt = 0; kt < 2; ++kt) {
            s16x8 af = *(const s16x8*)&As[b][(16 * w + c) * ASTR + kt * 32 + 8 * g];
            s16x8 wf0 = *(const s16x8*)&Ws[b][c * ASTR + kt * 32 + 8 * g];
            s16x8 wf1 = *(const s16x8*)&Ws[b][(16 + c) * ASTR + kt * 32 + 8 * g];
            acc[0] = __builtin_amdgcn_mfma_f32_16x16x32_bf16(af, wf0, acc[0], 0, 0, 0);
            acc[1] = __builtin_amdgcn_mfma_f32_16x16x32_bf16(af, wf1, acc[1], 0, 0, 0);
        }
        if (pf) {
            int nb = b ^ 1;
            *(s16x8*)&As[nb][srow * ASTR + cg8] = ra0;
            *(s16x8*)&As[nb][(16 + srow) * ASTR + cg8] = ra1;
            *(s16x8*)&Ws[nb][srow * ASTR + cg8] = rw0;
            *(s16x8*)&Ws[nb][(16 + srow) * ASTR + cg8] = rw1;
        }
        __syncthreads();
    }

#pragma unroll
    for (int nt = 0; nt < 2; ++nt) {
        int n = n0 + 16 * nt + c;
        float bv = bias[n];
        float sc = 1.f;
        if (EPI == 3) sc = (n < 256) ? 0.17677669529663687f : 1.f;
#pragma unroll
        for (int r = 0; r < 4; ++r) {
            int m = m0 + 16 * w + 4 * g + r;
            float v = acc[nt][r] + bv;
            if (EPI == 1) v = fmaxf(v, 0.f);
            if (EPI == 2) v += res[(size_t)m * N + n];
            if (EPI == 3) v *= sc;
            if (OUTBF) ((ushort_t*)outv)[(size_t)m * N + n] = f2bf(v);
            else ((float*)outv)[(size_t)m * N + n] = v;
        }
    }
}

// ---------------------------------------------------------------------------
// Split-KV MFMA flash attention, both levels in one launch (1280 blocks).
// lvl2: blocks 0..1023  = qt(32) x h(8) x split(4)
// lvl3: blocks 1024..1279 = qt(8) x h(8) x split(4)
// Writes unnormalized partial O (f32) + (m,l) per (split, q-row, head).
// ---------------------------------------------------------------------------
#define QS 40
#define KS 40
#define VS 72
#define PS 80
#define OS 68

__global__ __launch_bounds__(256) void flash_split(const ushort_t* __restrict__ qkvb,
                                                   const float* __restrict__ u2,
                                                   const float* __restrict__ u3,
                                                   float* __restrict__ Opart,
                                                   float2* __restrict__ ml) {
    __shared__ __align__(16) ushort_t qs[64 * QS];
    __shared__ __align__(16) ushort_t ks[2][64 * KS];
    __shared__ __align__(16) ushort_t vts[2][32 * VS];
    __shared__ __align__(16) char pso[64 * PS * 2];
    ushort_t* ps = (ushort_t*)pso;
    float* os = (float*)pso;

    const int bx = blockIdx.x;
    int qt, h, split, L, sshift, rowbase;
    const float* uu;
    if (bx < 1024) {
        qt = bx & 31; h = (bx >> 5) & 7; split = bx >> 8;
        L = 2048; sshift = 10; rowbase = 0; uu = u2;
    } else {
        int lo = bx - 1024;
        qt = lo & 7; h = (lo >> 3) & 7; split = lo >> 6;
        L = 512; sshift = 8; rowbase = 2048; uu = u3;
    }
    const int tps = (L >> 6) >> 2;      // tiles per split: 8 or 2
    const int ts0 = split * tps;

    const int t = threadIdx.x;
    const int w = t >> 6;
    const int l = t & 63;
    const int c = l & 15;
    const int g = l >> 4;
    const int smask = (1 << sshift) - 1;

    const int srow = t >> 2;
    const int sc8 = (t & 3) * 8;
    const int q0g = rowbase + qt * 64;

    *(s16x8*)&qs[srow * QS + sc8] =
        *(const s16x8*)&qkvb[(size_t)(q0g + srow) * 768 + h * 32 + sc8];

    {
        size_t base = (size_t)(rowbase + ts0 * 64 + srow) * 768 + h * 32 + sc8;
        s16x8 kreg = *(const s16x8*)&qkvb[base + 256];
        s16x8 vreg = *(const s16x8*)&qkvb[base + 512];
        *(s16x8*)&ks[0][srow * KS + sc8] = kreg;
#pragma unroll
        for (int i = 0; i < 8; ++i)
            vts[0][(sc8 + i) * VS + srow] = (ushort_t)vreg[i];
    }
    __syncthreads();

    const s16x8 qf = *(const s16x8*)&qs[(16 * w + c) * QS + 8 * g];
    const int ql = qt * 64 + 16 * w + c;     // level-local q row
    const int qp = ql & smask, qfr = ql >> sshift;

    f32x4 oacc0 = {0.f, 0.f, 0.f, 0.f};
    f32x4 oacc1 = {0.f, 0.f, 0.f, 0.f};
    float mold = -3e38f, lrun = 0.f;
    const f32x4 zc = {0.f, 0.f, 0.f, 0.f};

    for (int kt = 0; kt < tps; ++kt) {
        const int bb = kt & 1;
        const int k0 = (ts0 + kt) << 6;      // level-local kv offset
        const bool pf = (kt + 1 < tps);
        s16x8 kreg, vreg;
        if (pf) {
            size_t base = (size_t)(rowbase + k0 + 64 + srow) * 768 + h * 32 + sc8;
            kreg = *(const s16x8*)&qkvb[base + 256];
            vreg = *(const s16x8*)&qkvb[base + 512];
        }

        f32x4 sacc[4];
#pragma unroll
        for (int nt = 0; nt < 4; ++nt) {
            s16x8 kf = *(const s16x8*)&ks[bb][(16 * nt + c) * KS + 8 * g];
            sacc[nt] = __builtin_amdgcn_mfma_f32_16x16x32_bf16(kf, qf, zc, 0, 0, 0);
        }

        const float* urow = &uu[(size_t)ql * L + k0];
        float sv[4][4];
        float m = -3e38f;
#pragma unroll
        for (int nt = 0; nt < 4; ++nt) {
            f32x4 uv = *(const f32x4*)&urow[16 * nt + 4 * g];
#pragma unroll
            for (int r = 0; r < 4; ++r) {
                int kg = k0 + 16 * nt + 4 * g + r;
                float s = sacc[nt][r]
                        + (uv[r] >= 0.1f ? 1.f : 0.f)
                        + ((kg & smask) == qp ? 1.f : 0.f)
                        + ((kg >> sshift) == qfr ? 1.f : 0.f);
                sv[nt][r] = s;
                m = fmaxf(m, s);
            }
        }
        m = fmaxf(m, __shfl_xor(m, 16));
        m = fmaxf(m, __shfl_xor(m, 32));
        float newm = fmaxf(mold, m);
        float fac = __expf(mold - newm);
        mold = newm;

        float sum = 0.f;
#pragma unroll
        for (int nt = 0; nt < 4; ++nt) {
            float p0 = __expf(sv[nt][0] - newm);
            float p1 = __expf(sv[nt][1] - newm);
            float p2 = __expf(sv[nt][2] - newm);
            float p3 = __expf(sv[nt][3] - newm);
            sum += (p0 + p1) + (p2 + p3);
            u32x2 pk;
            pk[0] = ((unsigned)f2bf(p1) << 16) | f2bf(p0);
            pk[1] = ((unsigned)f2bf(p3) << 16) | f2bf(p2);
            *(u32x2*)&ps[(16 * w + c) * PS + 16 * nt + 4 * g] = pk;
        }
        sum += __shfl_xor(sum, 16);
        sum += __shfl_xor(sum, 32);
        lrun = lrun * fac + sum;
        oacc0 *= fac;
        oacc1 *= fac;

#pragma unroll
        for (int kc = 0; kc < 2; ++kc) {
            s16x8 pfr = *(const s16x8*)&ps[(16 * w + c) * PS + 32 * kc + 8 * g];
            s16x8 vf0 = *(const s16x8*)&vts[bb][c * VS + 32 * kc + 8 * g];
            s16x8 vf1 = *(const s16x8*)&vts[bb][(16 + c) * VS + 32 * kc + 8 * g];
            oacc0 = __builtin_amdgcn_mfma_f32_16x16x32_bf16(vf0, pfr, oacc0, 0, 0, 0);
            oacc1 = __builtin_amdgcn_mfma_f32_16x16x32_bf16(vf1, pfr, oacc1, 0, 0, 0);
        }

        __syncthreads();
        if (pf) {
            int nb = bb ^ 1;
            *(s16x8*)&ks[nb][srow * KS + sc8] = kreg;
#pragma unroll
            for (int i = 0; i < 8; ++i)
                vts[nb][(sc8 + i) * VS + srow] = (ushort_t)vreg[i];
        }
        __syncthreads();
    }

    // write (m, l) once per q-row (lanes with g==0)
    if (g == 0) {
        int q = q0g + 16 * w + c;
        ml[((size_t)split * RTOT + q) * 8 + h] = make_float2(mold, lrun);
    }

    // unnormalized partial O via LDS transpose, coalesced f32 write
#pragma unroll
    for (int r = 0; r < 4; ++r) {
        os[(4 * g + r) * OS + 16 * w + c] = oacc0[r];
        os[(16 + 4 * g + r) * OS + 16 * w + c] = oacc1[r];
    }
    __syncthreads();
    {
        int r = t >> 2, d0 = (t & 3) * 8;
        float* op = &Opart[((size_t)split * RTOT + q0g + r) * 256 + h * 32 + d0];
        f32x4 w0, w1;
#pragma unroll
        for (int i = 0; i < 4; ++i) w0[i] = os[(d0 + i) * OS + r];
#pragma unroll
        for (int i = 0; i < 4; ++i) w1[i] = os[(d0 + 4 + i) * OS + r];
        *(f32x4*)op = w0;
        *(f32x4*)(op + 4) = w1;
    }
}

// merge 4 split partials -> bf16 attention output [2560,256]
__global__ __launch_bounds__(256) void flash_merge(const float* __restrict__ Opart,
                                                   const float2* __restrict__ ml,
                                                   ushort_t* __restrict__ obuf) {
    int r = blockIdx.x, t = threadIdx.x;
    int h = t >> 5;
    float2 m0 = ml[((size_t)0 * RTOT + r) * 8 + h];
    float2 m1 = ml[((size_t)1 * RTOT + r) * 8 + h];
    float2 m2 = ml[((size_t)2 * RTOT + r) * 8 + h];
    float2 m3 = ml[((size_t)3 * RTOT + r) * 8 + h];
    float ms = fmaxf(fmaxf(m0.x, m1.x), fmaxf(m2.x, m3.x));
    float w0 = __expf(m0.x - ms), w1 = __expf(m1.x - ms);
    float w2 = __expf(m2.x - ms), w3 = __expf(m3.x - ms);
    float denom = w0 * m0.y + w1 * m1.y + w2 * m2.y + w3 * m3.y;
    size_t idx = (size_t)r * 256 + t;
    const size_t stride = (size_t)RTOT * 256;
    float v = w0 * Opart[idx] + w1 * Opart[idx + stride]
            + w2 * Opart[idx + 2 * stride] + w3 * Opart[idx + 3 * stride];
    obuf[idx] = f2bf(v / denom);
}

// LayerNorm over C=256, one block per row; optional bf16 copy
template <int WB>
__global__ __launch_bounds__(256) void ln_kernel(const float* __restrict__ in,
                                                 const float* __restrict__ g,
                                                 const float* __restrict__ b,
                                                 float* __restrict__ outf,
                                                 ushort_t* __restrict__ outb) {
    __shared__ float red[256];
    int row = blockIdx.x, t = threadIdx.x;
    float v = in[(size_t)row * 256 + t];
    red[t] = v;
    __syncthreads();
    for (int s = 128; s > 0; s >>= 1) {
        if (t < s) red[t] += red[t + s];
        __syncthreads();
    }
    float mean = red[0] * (1.f / 256.f);
    __syncthreads();
    float d = v - mean;
    red[t] = d * d;
    __syncthreads();
    for (int s = 128; s > 0; s >>= 1) {
        if (t < s) red[t] += red[t + s];
        __syncthreads();
    }
    float var = red[0] * (1.f / 256.f);
    float r = d * rsqrtf(var + 1e-5f) * g[t] + b[t];
    outf[(size_t)row * 256 + t] = r;
    if (WB) outb[(size_t)row * 256 + t] = f2bf(r);
}

// ---------------------------------------------------------------------------

extern "C" void kernel_launch(void* const* d_in, const int* in_sizes, int n_in,
                              void* d_out, int out_size, void* d_ws, size_t ws_size,
                              hipStream_t stream) {
    const float* f0 = (const float*)d_in[0];
    const float* f1 = (const float*)d_in[1];
    const float* f2 = (const float*)d_in[2];
    const float* f3 = (const float*)d_in[3];
    const float* u2 = (const float*)d_in[4];
    const float* u3 = (const float*)d_in[5];
    const float* Wqkv = (const float*)d_in[6];
    const float* bqkv = (const float*)d_in[7];
    const float* Wo   = (const float*)d_in[8];
    const float* bo   = (const float*)d_in[9];
    const float* g1   = (const float*)d_in[10];
    const float* b1   = (const float*)d_in[11];
    const float* Wfc1 = (const float*)d_in[12];
    const float* bfc1 = (const float*)d_in[13];
    const float* Wfc2 = (const float*)d_in[14];
    const float* bfc2 = (const float*)d_in[15];
    const float* g2   = (const float*)d_in[16];
    const float* b2   = (const float*)d_in[17];

    float* out = (float*)d_out;
    float* ws = (float*)d_ws;

    // bf16 weights
    ushort_t* wqkv = (ushort_t*)ws;             // 196608 us
    ushort_t* wo   = (ushort_t*)(ws + 98304);   // 65536 us
    ushort_t* wfc1 = (ushort_t*)(ws + 131072);  // 262144 us
    ushort_t* wfc2 = (ushort_t*)(ws + 262144);  // 262144 us

    // scratch (floats), R = 2560 rows
    float* sc = ws + 393216;
    float*    src_f32 = sc;                          // 655360
    ushort_t* qkvb    = (ushort_t*)(sc + 655360);    // 2560*768 us
    ushort_t* obuf    = (ushort_t*)(sc + 1638400);   // 2560*256 us (src_bf alias)
    ushort_t* src_bf  = obuf;
    float*    t1      = sc + 1966080;                // 655360
    float*    x_f32   = sc + 2621440;                // 655360
    ushort_t* x_bf    = (ushort_t*)(sc + 3276800);   // 2560*256 us
    float2*   ml      = (float2*)(sc + 3604480);     // 4*2560*8 f2
    float*    Opart   = sc + 3768320;                // 4*2560*256 f32
    ushort_t* h_bf    = (ushort_t*)Opart;            // 2560*1024 us (alias)
    float*    y       = src_f32;                     // reuse

    cvt_all<<<768, 256, 0, stream>>>(Wqkv, Wo, Wfc1, Wfc2, wqkv, wo, wfc1, wfc2);

    hipMemcpyAsync(out, f0, (size_t)3276800 * 4, hipMemcpyDeviceToDevice, stream);
    hipMemcpyAsync(out + 3276800, f1, (size_t)819200 * 4, hipMemcpyDeviceToDevice, stream);

    nchw_in<<<2560, 256, 0, stream>>>(f2, f3, src_f32, src_bf);
    gemm32<3, 1><<<dim3(24, 80), 128, 0, stream>>>(
        src_bf, wqkv, bqkv, nullptr, qkvb, RTOT, 768, 256);
    flash_split<<<1280, 256, 0, stream>>>(qkvb, u2, u3, Opart, ml);
    flash_merge<<<2560, 256, 0, stream>>>(Opart, ml, obuf);
    gemm32<2, 0><<<dim3(8, 80), 128, 0, stream>>>(
        obuf, wo, bo, src_f32, t1, RTOT, 256, 256);
    ln_kernel<1><<<2560, 256, 0, stream>>>(t1, g1, b1, x_f32, x_bf);
    gemm32<1, 1><<<dim3(32, 80), 128, 0, stream>>>(
        x_bf, wfc1, bfc1, nullptr, h_bf, RTOT, 1024, 256);
    gemm32<2, 0><<<dim3(8, 80), 128, 0, stream>>>(
        h_bf, wfc2, bfc2, x_f32, t1, RTOT, 256, 1024);
    ln_kernel<0><<<2560, 256, 0, stream>>>(t1, g2, b2, y, nullptr);
    lc_out<<<2560, 256, 0, stream>>>(y, out + 4096000, out + 4620288);
}